// Round 2
// baseline (533.004 us; speedup 1.0000x reference)
//
#include <hip/hip_runtime.h>
#include <hip/hip_bf16.h>

typedef __bf16 bf16_t;
typedef __bf16 bf16x8 __attribute__((ext_vector_type(8)));
typedef float  f32x4  __attribute__((ext_vector_type(4)));

#define N_NODES 100000
#define N_EDGES 1600000
#define IN_C    128
#define OUT_C   64
#define EDGE_D  64

// ---------------- Kernel A: node GEMM (k,q,v,skip) ----------------
// wave w: 0=key,1=query,2=value,3=skip. k,q,v -> bf16 tables in ws;
// skip+bias -> f32 agg (acts as segment_sum init, no memset needed).
__global__ __launch_bounds__(256) void node_gemm_kernel(
    const float* __restrict__ x,
    const float* __restrict__ Wk, const float* __restrict__ bk,
    const float* __restrict__ Wq, const float* __restrict__ bq,
    const float* __restrict__ Wv, const float* __restrict__ bv,
    const float* __restrict__ Ws, const float* __restrict__ bs,
    bf16_t* __restrict__ kqv,   // [3][N][64] bf16
    float*  __restrict__ agg)   // [N][64] f32
{
    const int w  = threadIdx.x >> 6;
    const int l  = threadIdx.x & 63;
    const int lr = l & 15;
    const int lg = l >> 4;

    const float* W; const float* b;
    if      (w == 0) { W = Wk; b = bk; }
    else if (w == 1) { W = Wq; b = bq; }
    else if (w == 2) { W = Wv; b = bv; }
    else             { W = Ws; b = bs; }

    // B fragment: B[k][n], k = ks*32 + lg*8 + j, n = ct*16 + lr
    bf16x8 Bf[4][4];
    #pragma unroll
    for (int ct = 0; ct < 4; ++ct)
        #pragma unroll
        for (int ks = 0; ks < 4; ++ks)
            #pragma unroll
            for (int j = 0; j < 8; ++j)
                Bf[ct][ks][j] = (bf16_t)W[(ks*32 + lg*8 + j)*OUT_C + ct*16 + lr];

    float biasv[4];
    #pragma unroll
    for (int ct = 0; ct < 4; ++ct) biasv[ct] = b[ct*16 + lr];

    const int NTILES = N_NODES / 32;  // 3125
    for (int tile = blockIdx.x; tile < NTILES; tile += gridDim.x) {
        const int n0 = tile * 32;
        f32x4 acc[2][4];
        #pragma unroll
        for (int rt = 0; rt < 2; ++rt)
            #pragma unroll
            for (int ct = 0; ct < 4; ++ct)
                acc[rt][ct] = (f32x4){0.f, 0.f, 0.f, 0.f};

        #pragma unroll
        for (int ks = 0; ks < 4; ++ks) {
            // A fragment: A[m][k], m = row, k = ks*32 + lg*8 + j  (f32 -> bf16)
            const float* p0 = x + (size_t)(n0 + lr)      * IN_C + ks*32 + lg*8;
            const float* p1 = x + (size_t)(n0 + 16 + lr) * IN_C + ks*32 + lg*8;
            f32x4 v00 = *reinterpret_cast<const f32x4*>(p0);
            f32x4 v01 = *reinterpret_cast<const f32x4*>(p0 + 4);
            f32x4 v10 = *reinterpret_cast<const f32x4*>(p1);
            f32x4 v11 = *reinterpret_cast<const f32x4*>(p1 + 4);
            bf16x8 a0, a1;
            #pragma unroll
            for (int j = 0; j < 4; ++j) {
                a0[j] = (bf16_t)v00[j]; a0[4+j] = (bf16_t)v01[j];
                a1[j] = (bf16_t)v10[j]; a1[4+j] = (bf16_t)v11[j];
            }
            #pragma unroll
            for (int ct = 0; ct < 4; ++ct) {
                acc[0][ct] = __builtin_amdgcn_mfma_f32_16x16x32_bf16(a0, Bf[ct][ks], acc[0][ct], 0, 0, 0);
                acc[1][ct] = __builtin_amdgcn_mfma_f32_16x16x32_bf16(a1, Bf[ct][ks], acc[1][ct], 0, 0, 0);
            }
        }

        // C/D layout: col = lane&15, row = (lane>>4)*4 + reg   [m89-verified]
        #pragma unroll
        for (int rt = 0; rt < 2; ++rt)
            #pragma unroll
            for (int ct = 0; ct < 4; ++ct)
                #pragma unroll
                for (int r = 0; r < 4; ++r) {
                    const int row = n0 + rt*16 + lg*4 + r;
                    const int col = ct*16 + lr;
                    const float val = acc[rt][ct][r] + biasv[ct];
                    if (w < 3) kqv[(size_t)w * N_NODES * OUT_C + (size_t)row * OUT_C + col] = (bf16_t)val;
                    else       agg[(size_t)row * OUT_C + col] = val;
                }
    }
}

// ---------------- Kernel B: fused edge kernel ----------------
// Per wave: 16-edge tile. e = ea @ W_edge + b_edge via MFMA; fused copy of
// edge_attr to output; gather k[dst],q[src],v[src]; sigmoid gate; atomic agg.
__global__ __launch_bounds__(256) void edge_kernel(
    const float* __restrict__ ea,
    const int*   __restrict__ ei,     // [2][E]: row0=src(j), row1=dst(i)
    const float* __restrict__ We, const float* __restrict__ be,
    const bf16_t* __restrict__ kqv,
    float* __restrict__ agg,
    float* __restrict__ out_ea)
{
    const int l  = threadIdx.x & 63;
    const int lr = l & 15;
    const int lg = l >> 4;
    const int wid = blockIdx.x * 4 + (threadIdx.x >> 6);
    const int nw  = gridDim.x * 4;

    bf16x8 Bf[4][2];
    #pragma unroll
    for (int ct = 0; ct < 4; ++ct)
        #pragma unroll
        for (int ks = 0; ks < 2; ++ks)
            #pragma unroll
            for (int j = 0; j < 8; ++j)
                Bf[ct][ks][j] = (bf16_t)We[(ks*32 + lg*8 + j)*OUT_C + ct*16 + lr];

    float bev[4];
    #pragma unroll
    for (int ct = 0; ct < 4; ++ct) bev[ct] = be[ct*16 + lr];

    const bf16_t* kT = kqv;
    const bf16_t* qT = kqv + (size_t)N_NODES * OUT_C;
    const bf16_t* vT = kqv + (size_t)2 * N_NODES * OUT_C;

    const int NT = N_EDGES / 16;  // 100000
    for (int t = wid; t < NT; t += nw) {
        const int e0 = t * 16;

        // A fragments + fused f32 copy (each byte of the 16x64 tile touched once)
        bf16x8 a[2];
        #pragma unroll
        for (int ks = 0; ks < 2; ++ks) {
            const size_t off = (size_t)(e0 + lr) * EDGE_D + ks*32 + lg*8;
            f32x4 v0 = *reinterpret_cast<const f32x4*>(ea + off);
            f32x4 v1 = *reinterpret_cast<const f32x4*>(ea + off + 4);
            *reinterpret_cast<f32x4*>(out_ea + off)     = v0;
            *reinterpret_cast<f32x4*>(out_ea + off + 4) = v1;
            #pragma unroll
            for (int j = 0; j < 4; ++j) { a[ks][j] = (bf16_t)v0[j]; a[ks][4+j] = (bf16_t)v1[j]; }
        }

        f32x4 acc[4];
        #pragma unroll
        for (int ct = 0; ct < 4; ++ct) acc[ct] = (f32x4){0.f, 0.f, 0.f, 0.f};
        #pragma unroll
        for (int ct = 0; ct < 4; ++ct)
            #pragma unroll
            for (int ks = 0; ks < 2; ++ks)
                acc[ct] = __builtin_amdgcn_mfma_f32_16x16x32_bf16(a[ks], Bf[ct][ks], acc[ct], 0, 0, 0);

        // rows handled by this lane group: edge = e0 + lg*4 + r
        int srcR[4], dstR[4];
        #pragma unroll
        for (int r = 0; r < 4; ++r) {
            srcR[r] = ei[e0 + lg*4 + r];
            dstR[r] = ei[N_EDGES + e0 + lg*4 + r];
        }

        #pragma unroll
        for (int r = 0; r < 4; ++r) {
            #pragma unroll
            for (int ct = 0; ct < 4; ++ct) {
                const int col = ct*16 + lr;
                const float ev = acc[ct][r] + bev[ct];
                const float kd = (float)kT[(size_t)dstR[r] * OUT_C + col];
                const float qs = (float)qT[(size_t)srcR[r] * OUT_C + col];
                const float vs = (float)vT[(size_t)srcR[r] * OUT_C + col];
                const float z  = kd + qs + ev;
                const float gate = 1.f / (1.f + __expf(-z));
                atomicAdd(agg + (size_t)dstR[r] * OUT_C + col, gate * vs);
            }
        }
    }
}

// ---------------- Kernel C: finalize ----------------
__global__ __launch_bounds__(256) void finalize_kernel(
    const float* __restrict__ agg,
    const float* __restrict__ u,
    float* __restrict__ out_node,
    float* __restrict__ out_u)
{
    const int gid   = blockIdx.x * blockDim.x + threadIdx.x;
    const int total = N_NODES * OUT_C / 4;  // 1.6M groups of 4
    for (int i = gid; i < total; i += gridDim.x * blockDim.x) {
        f32x4 v = *reinterpret_cast<const f32x4*>(agg + (size_t)i * 4);
        f32x4 o;
        #pragma unroll
        for (int j = 0; j < 4; ++j) o[j] = v[j] > 0.f ? v[j] : 0.f;
        *reinterpret_cast<f32x4*>(out_node + (size_t)i * 4) = o;
    }
    if (gid < 64) out_u[gid] = u[gid];
}

extern "C" void kernel_launch(void* const* d_in, const int* in_sizes, int n_in,
                              void* d_out, int out_size, void* d_ws, size_t ws_size,
                              hipStream_t stream) {
    const float* x  = (const float*)d_in[0];
    const int*   ei = (const int*)  d_in[1];
    const float* ea = (const float*)d_in[2];
    const float* u  = (const float*)d_in[3];
    const float* Wk = (const float*)d_in[4];
    const float* bk = (const float*)d_in[5];
    const float* Wq = (const float*)d_in[6];
    const float* bq = (const float*)d_in[7];
    const float* Wv = (const float*)d_in[8];
    const float* bv = (const float*)d_in[9];
    const float* We = (const float*)d_in[10];
    const float* be = (const float*)d_in[11];
    const float* Ws = (const float*)d_in[12];
    const float* bs = (const float*)d_in[13];

    float* out      = (float*)d_out;
    float* out_node = out;
    float* out_ea   = out + (size_t)N_NODES * OUT_C;
    float* out_u    = out + (size_t)N_NODES * OUT_C + (size_t)N_EDGES * EDGE_D;

    // ws layout: kqv bf16 [3][N][64] (38.4 MB) | agg f32 [N][64] (25.6 MB)
    bf16_t* kqv = (bf16_t*)d_ws;
    float*  agg = (float*)((char*)d_ws + (size_t)3 * N_NODES * OUT_C * sizeof(bf16_t));

    node_gemm_kernel<<<1024, 256, 0, stream>>>(x, Wk, bk, Wq, bq, Wv, bv, Ws, bs, kqv, agg);
    edge_kernel<<<2048, 256, 0, stream>>>(ea, ei, We, be, kqv, agg, out_ea);
    finalize_kernel<<<2048, 256, 0, stream>>>(agg, u, out_node, out_u);
}